// Round 1
// baseline (186.215 us; speedup 1.0000x reference)
//
#include <hip/hip_runtime.h>

#define B 32
#define N 1024
#define D 256
#define H 8
#define E 256
#define P 8   // xbar partial slices

// -------- K1: xbar partials: xbar_part[b,p,d] = sum_{n in slice p} ws[n]*x[b,n,d]
__global__ __launch_bounds__(256) void k1_xbar(const float* __restrict__ x,
                                               const float* __restrict__ wsum,
                                               float* __restrict__ xbar_part) {
    int b = blockIdx.x, p = blockIdx.y, d = threadIdx.x;
    const float* xp = x + ((size_t)b * N + (size_t)p * (N / P)) * D + d;
    const float* wp = wsum + p * (N / P);
    float acc = 0.f;
#pragma unroll 4
    for (int n = 0; n < N / P; ++n) acc += wp[n] * xp[(size_t)n * D];
    xbar_part[((size_t)b * P + p) * D + d] = acc;
}

// -------- K2: per (b,h): kbar = Wk_h @ xbar + S*bk_h ; u = Wq_h^T @ kbar
__global__ __launch_bounds__(256) void k2_u(const float* __restrict__ Wq,
                                            const float* __restrict__ Wk,
                                            const float* __restrict__ bk,
                                            const float* __restrict__ wsum,
                                            const float* __restrict__ xbar_part,
                                            float* __restrict__ u_out) {
    __shared__ float xbar_s[D];
    __shared__ float kbar_s[E];
    __shared__ float red[256];
    int t = threadIdx.x;
    int b = blockIdx.x >> 3, h = blockIdx.x & 7;

    // finalize xbar
    float xa = 0.f;
#pragma unroll
    for (int p = 0; p < P; ++p) xa += xbar_part[((size_t)b * P + p) * D + t];
    xbar_s[t] = xa;

    // S = sum(ws)
    float sp = wsum[t] + wsum[t + 256] + wsum[t + 512] + wsum[t + 768];
    red[t] = sp;
    __syncthreads();
    for (int s = 128; s > 0; s >>= 1) {
        if (t < s) red[t] += red[t + s];
        __syncthreads();
    }
    float S = red[0];
    __syncthreads();

    // kbar[e] (thread e): dot(Wk row, xbar) + S*bk
    {
        const float4* wk4 = (const float4*)(Wk + (size_t)(h * E + t) * D);
        float acc = 0.f;
#pragma unroll 4
        for (int i = 0; i < D / 4; ++i) {
            float4 w = wk4[i];
            acc += w.x * xbar_s[4 * i] + w.y * xbar_s[4 * i + 1] +
                   w.z * xbar_s[4 * i + 2] + w.w * xbar_s[4 * i + 3];
        }
        kbar_s[t] = acc + S * bk[h * E + t];
    }
    __syncthreads();

    // u[d] (thread d): sum_e Wq[hE+e, d] * kbar[e]  (coalesced over d)
    {
        const float* wq = Wq + (size_t)h * E * D + t;
        float ua = 0.f;
#pragma unroll 4
        for (int e = 0; e < E; ++e) ua += wq[(size_t)e * D] * kbar_s[e];
        u_out[(size_t)blockIdx.x * D + t] = ua;
    }
}

// -------- K3: per (b,h): logits = scale*(x_n . u); softmax over n; vbar; result = Wv_h@vbar + bv_h
__global__ __launch_bounds__(512) void k3_attn(const float* __restrict__ x,
                                               const float* __restrict__ Wv,
                                               const float* __restrict__ bv,
                                               const float* __restrict__ u_in,
                                               float* __restrict__ result) {
    __shared__ float u_s[D];        // u, later reused as vbar
    __shared__ float e_s[N];        // logits -> exp weights
    __shared__ float red[512];
    __shared__ float vb_s[8][D];    // per-wave vbar partials
    int t = threadIdx.x;
    int h = blockIdx.x & 7;
    int b = blockIdx.x >> 3;
    int wave = t >> 6, lane = t & 63;

    if (t < D) u_s[t] = u_in[(size_t)blockIdx.x * D + t];
    __syncthreads();

    float4 u4 = *(const float4*)&u_s[lane * 4];
    const float4* xb4 = (const float4*)(x + (size_t)b * N * D);
    const float scale = 0.0625f;  // 1/sqrt(256)

    // dot pass: each wave owns 128 rows, 2 per iter for ILP
    int n0 = wave * 128;
    for (int i = 0; i < 128; i += 2) {
        float4 xa = xb4[(size_t)(n0 + i) * 64 + lane];
        float4 xc = xb4[(size_t)(n0 + i + 1) * 64 + lane];
        float da = xa.x * u4.x + xa.y * u4.y + xa.z * u4.z + xa.w * u4.w;
        float dc = xc.x * u4.x + xc.y * u4.y + xc.z * u4.z + xc.w * u4.w;
#pragma unroll
        for (int off = 32; off > 0; off >>= 1) {
            da += __shfl_xor(da, off);
            dc += __shfl_xor(dc, off);
        }
        if (lane == 0) {
            e_s[n0 + i] = da * scale;
            e_s[n0 + i + 1] = dc * scale;
        }
    }
    __syncthreads();

    // softmax over N=1024 (constants cancel; max-subtracted)
    float m2 = fmaxf(e_s[t], e_s[t + 512]);
    red[t] = m2;
    __syncthreads();
    for (int s = 256; s > 0; s >>= 1) {
        if (t < s) red[t] = fmaxf(red[t], red[t + s]);
        __syncthreads();
    }
    float M = red[0];
    __syncthreads();
    float z0 = __expf(e_s[t] - M), z1 = __expf(e_s[t + 512] - M);
    e_s[t] = z0;
    e_s[t + 512] = z1;
    red[t] = z0 + z1;
    __syncthreads();
    for (int s = 256; s > 0; s >>= 1) {
        if (t < s) red[t] += red[t + s];
        __syncthreads();
    }
    float invS = 1.0f / red[0];
    __syncthreads();

    // vbar pass: acc += e[n] * x[n, :]
    float4 acc = make_float4(0.f, 0.f, 0.f, 0.f);
    for (int i = 0; i < 128; ++i) {
        int n = n0 + i;
        float be = e_s[n];
        float4 xv = xb4[(size_t)n * 64 + lane];
        acc.x += be * xv.x;
        acc.y += be * xv.y;
        acc.z += be * xv.z;
        acc.w += be * xv.w;
    }
    *(float4*)&vb_s[wave][lane * 4] = acc;
    __syncthreads();

    if (t < D) {
        float vb = 0.f;
#pragma unroll
        for (int w = 0; w < 8; ++w) vb += vb_s[w][t];
        u_s[t] = vb * invS;  // u4 regs already hold u; safe to reuse
    }
    __syncthreads();

    // result[e] = Wv_h[e,:] . vbar + bv
    if (t < E) {
        const float4* wv4 = (const float4*)(Wv + (size_t)(h * E + t) * D);
        float racc = bv[h * E + t];
#pragma unroll 4
        for (int i = 0; i < 64; ++i) {
            float4 w = wv4[i];
            racc += w.x * u_s[4 * i] + w.y * u_s[4 * i + 1] +
                    w.z * u_s[4 * i + 2] + w.w * u_s[4 * i + 3];
        }
        result[(size_t)blockIdx.x * E + t] = racc;
    }
}

// -------- K4: out[b,:] = Wo @ result_flat[b] + bo
__global__ __launch_bounds__(256) void k4_out(const float* __restrict__ Wo,
                                              const float* __restrict__ bo,
                                              const float* __restrict__ res,
                                              float* __restrict__ out) {
    __shared__ float r_s[H * E];
    int t = threadIdx.x, b = blockIdx.x;
#pragma unroll
    for (int k = 0; k < H * E; k += 256) r_s[k + t] = res[(size_t)b * (H * E) + k + t];
    __syncthreads();
    const float4* wo4 = (const float4*)(Wo + (size_t)t * (H * E));
    float acc = bo[t];
#pragma unroll 4
    for (int i = 0; i < (H * E) / 4; ++i) {
        float4 w = wo4[i];
        acc += w.x * r_s[4 * i] + w.y * r_s[4 * i + 1] +
               w.z * r_s[4 * i + 2] + w.w * r_s[4 * i + 3];
    }
    out[(size_t)b * D + t] = acc;
}

extern "C" void kernel_launch(void* const* d_in, const int* in_sizes, int n_in,
                              void* d_out, int out_size, void* d_ws, size_t ws_size,
                              hipStream_t stream) {
    const float* x    = (const float*)d_in[0];
    const float* Wq   = (const float*)d_in[1];
    // d_in[2] = bq : cancels in softmax (constant per (b,h))
    const float* Wk   = (const float*)d_in[3];
    const float* bk   = (const float*)d_in[4];
    const float* Wv   = (const float*)d_in[5];
    const float* bv   = (const float*)d_in[6];
    const float* wsum = (const float*)d_in[7];
    // d_in[8] = bs : cancels in softmax
    const float* Wo   = (const float*)d_in[9];
    const float* bo   = (const float*)d_in[10];
    float* out = (float*)d_out;

    float* u_buf  = (float*)d_ws;           // B*H*D floats
    float* xr_buf = u_buf + (size_t)B * H * D;  // B*P*D floats (xbar partials), reused as result B*H*E

    k1_xbar<<<dim3(B, P), 256, 0, stream>>>(x, wsum, xr_buf);
    k2_u<<<B * H, 256, 0, stream>>>(Wq, Wk, bk, wsum, xr_buf, u_buf);
    k3_attn<<<B * H, 512, 0, stream>>>(x, Wv, bv, u_buf, xr_buf);
    k4_out<<<B, 256, 0, stream>>>(Wo, bo, xr_buf, out);
}

// Round 2
// 83.919 us; speedup vs baseline: 2.2190x; 2.2190x over previous
//
#include <hip/hip_runtime.h>

#define B 32
#define N 1024
#define D 256
#define H 8
#define E 256
#define HE 2048

// d_ws float offsets
#define OFF_XBAR 0        // [B][D]            8192
#define OFF_VBAR 8192     // [B][H][D]         65536  (zeroed with XBAR)
#define OFF_KBAR 73728    // [B][HE]           65536
#define OFF_U    139264   // [B][H][D]         65536
#define OFF_LOG  204800   // [B][H][N]         262144 (reused in-place as beta)
#define OFF_RES  466944   // [B][HE]           65536

#define DOT4(a, v) ((a).x * (v).x + (a).y * (v).y + (a).z * (v).z + (a).w * (v).w)

// ---- xbar[b,d] = sum_n wsum[n] * x[b,n,d]  (atomic partials from 8 n-chunks)
__global__ __launch_bounds__(256) void k_xbar(const float4* __restrict__ x4,
                                              const float* __restrict__ wsum,
                                              float* __restrict__ Xbar) {
    __shared__ float4 ps[4][64];
    int t = threadIdx.x, b = blockIdx.x, p = blockIdx.y;
    int dq = t & 63, rep = t >> 6;
    float4 acc = make_float4(0.f, 0.f, 0.f, 0.f);
    int nbase = p * 128 + rep * 32;
#pragma unroll 4
    for (int i = 0; i < 32; ++i) {
        int n = nbase + i;
        float w = wsum[n];  // uniform -> s_load
        float4 xv = x4[(size_t)(b * N + n) * 64 + dq];
        acc.x += w * xv.x; acc.y += w * xv.y; acc.z += w * xv.z; acc.w += w * xv.w;
    }
    ps[rep][dq] = acc;
    __syncthreads();
    if (t < 64) {
        float4 s = ps[0][t];
        float4 s1 = ps[1][t], s2 = ps[2][t], s3 = ps[3][t];
        s.x += s1.x + s2.x + s3.x; s.y += s1.y + s2.y + s3.y;
        s.z += s1.z + s2.z + s3.z; s.w += s1.w + s2.w + s3.w;
        float* xp = &Xbar[b * D + t * 4];
        atomicAdd(xp + 0, s.x); atomicAdd(xp + 1, s.y);
        atomicAdd(xp + 2, s.z); atomicAdd(xp + 3, s.w);
    }
}

// ---- Kbar[b, he] = Wk[he,:].Xbar[b,:] + S*bk[he]
__global__ __launch_bounds__(256) void k_kbar(const float4* __restrict__ Wk4,
                                              const float* __restrict__ bk,
                                              const float* __restrict__ wsum,
                                              const float4* __restrict__ Xbar4,
                                              float* __restrict__ Kbar) {
    __shared__ float Xs[32][260];
    __shared__ float Wks[16][260];
    __shared__ float red[256];
    int t = threadIdx.x, he0 = blockIdx.x * 16;
    // S = sum(wsum)
    red[t] = wsum[t] + wsum[t + 256] + wsum[t + 512] + wsum[t + 768];
    __syncthreads();
    for (int s = 128; s > 0; s >>= 1) {
        if (t < s) red[t] += red[t + s];
        __syncthreads();
    }
    float S = red[0];
#pragma unroll
    for (int j = 0; j < 8; ++j) {
        int i4 = t + j * 256, r = i4 >> 6, c = i4 & 63;
        *(float4*)&Xs[r][c * 4] = Xbar4[r * 64 + c];
    }
#pragma unroll
    for (int j = 0; j < 4; ++j) {
        int i4 = t + j * 256, r = i4 >> 6, c = i4 & 63;
        *(float4*)&Wks[r][c * 4] = Wk4[(size_t)(he0 + r) * 64 + c];
    }
    __syncthreads();
    int b = t & 31, rr = t >> 5;
    float a0 = 0.f, a1 = 0.f;
#pragma unroll 4
    for (int c = 0; c < 64; ++c) {
        float4 xv = *(float4*)&Xs[b][c * 4];
        float4 w0 = *(float4*)&Wks[rr][c * 4];
        float4 w1 = *(float4*)&Wks[rr + 8][c * 4];
        a0 += DOT4(w0, xv);
        a1 += DOT4(w1, xv);
    }
    Kbar[(size_t)b * HE + he0 + rr] = a0 + S * bk[he0 + rr];
    Kbar[(size_t)b * HE + he0 + rr + 8] = a1 + S * bk[he0 + rr + 8];
}

// ---- u[b,h,d] = scale * sum_e Wq[h*E+e, d] * Kbar[b, h*E+e]
__global__ __launch_bounds__(256) void k_u(const float4* __restrict__ Wq4,
                                           const float* __restrict__ Kbar,
                                           float* __restrict__ u) {
    __shared__ float4 ps[4][64][9];
    int t = threadIdx.x, h = blockIdx.x, bg = blockIdx.y;
    int dq = t & 63, rep = t >> 6;
    float4 acc[8];
#pragma unroll
    for (int j = 0; j < 8; ++j) acc[j] = make_float4(0.f, 0.f, 0.f, 0.f);
    for (int el = 0; el < 64; ++el) {
        int e = rep * 64 + el;
        float4 wq = Wq4[(size_t)(h * E + e) * 64 + dq];
#pragma unroll
        for (int j = 0; j < 8; ++j) {
            float kb = Kbar[(size_t)(bg * 8 + j) * HE + h * E + e];  // uniform
            acc[j].x += kb * wq.x; acc[j].y += kb * wq.y;
            acc[j].z += kb * wq.z; acc[j].w += kb * wq.w;
        }
    }
#pragma unroll
    for (int j = 0; j < 8; ++j) ps[rep][dq][j] = acc[j];
    __syncthreads();
    int js = t >> 6;
#pragma unroll
    for (int jj = 0; jj < 2; ++jj) {
        int j = js * 2 + jj;
        float4 s = ps[0][dq][j], s1 = ps[1][dq][j], s2 = ps[2][dq][j], s3 = ps[3][dq][j];
        s.x = (s.x + s1.x + s2.x + s3.x) * 0.0625f;
        s.y = (s.y + s1.y + s2.y + s3.y) * 0.0625f;
        s.z = (s.z + s1.z + s2.z + s3.z) * 0.0625f;
        s.w = (s.w + s1.w + s2.w + s3.w) * 0.0625f;
        *(float4*)&u[((size_t)(bg * 8 + j) * 8 + h) * D + dq * 4] = s;
    }
}

// ---- logits[b,h,n] = x[b,n,:].u[b,h,:]   (scale folded into u)
__global__ __launch_bounds__(256) void k_logits(const float4* __restrict__ x4,
                                                const float* __restrict__ u,
                                                float* __restrict__ logit) {
    __shared__ float xs[64][260];
    __shared__ float ps[4][64][9];
    int t = threadIdx.x, b = blockIdx.x, n0 = blockIdx.y * 64;
#pragma unroll
    for (int j = 0; j < 16; ++j) {
        int i4 = t + j * 256, r = i4 >> 6, c = i4 & 63;
        *(float4*)&xs[r][c * 4] = x4[(size_t)(b * N + n0 + r) * 64 + c];
    }
    __syncthreads();
    int w = t >> 6, lane = t & 63;
    const float* ub = u + (size_t)b * HE;
    float acc[8] = {0.f, 0.f, 0.f, 0.f, 0.f, 0.f, 0.f, 0.f};
    for (int g = 0; g < 16; ++g) {
        int d = w * 64 + g * 4;
        float4 xv = *(float4*)&xs[lane][d];
#pragma unroll
        for (int h = 0; h < 8; ++h) {
            float4 uv = *(const float4*)&ub[h * D + d];  // uniform -> s_load_dwordx4
            acc[h] += DOT4(xv, uv);
        }
    }
#pragma unroll
    for (int h = 0; h < 8; ++h) ps[w][lane][h] = acc[h];
    __syncthreads();
#pragma unroll
    for (int k = 0; k < 2; ++k) {
        int p = t + k * 256, r = p & 63, h = p >> 6;
        float s = ps[0][r][h] + ps[1][r][h] + ps[2][r][h] + ps[3][r][h];
        logit[((size_t)b * H + h) * N + n0 + r] = s;
    }
}

// ---- softmax over n, in place (per (b,h))
__global__ __launch_bounds__(256) void k_softmax(float* __restrict__ logit) {
    __shared__ float red[256];
    int t = threadIdx.x;
    float* base = logit + (size_t)blockIdx.x * N;
    float v0 = base[t], v1 = base[t + 256], v2 = base[t + 512], v3 = base[t + 768];
    red[t] = fmaxf(fmaxf(v0, v1), fmaxf(v2, v3));
    __syncthreads();
    for (int s = 128; s > 0; s >>= 1) {
        if (t < s) red[t] = fmaxf(red[t], red[t + s]);
        __syncthreads();
    }
    float M = red[0];
    __syncthreads();
    float e0 = __expf(v0 - M), e1 = __expf(v1 - M), e2 = __expf(v2 - M), e3 = __expf(v3 - M);
    red[t] = e0 + e1 + e2 + e3;
    __syncthreads();
    for (int s = 128; s > 0; s >>= 1) {
        if (t < s) red[t] += red[t + s];
        __syncthreads();
    }
    float inv = 1.0f / red[0];
    base[t] = e0 * inv; base[t + 256] = e1 * inv;
    base[t + 512] = e2 * inv; base[t + 768] = e3 * inv;
}

// ---- vbar[b,h,d] = sum_n beta[b,h,n] * x[b,n,d]  (atomic partials from 8 n-chunks)
__global__ __launch_bounds__(256) void k_vbar(const float4* __restrict__ x4,
                                              const float* __restrict__ beta,
                                              float* __restrict__ vbar) {
    __shared__ float4 ps[4][64][9];
    int t = threadIdx.x, b = blockIdx.x, ch = blockIdx.y;
    int dq = t & 63, rep = t >> 6;
    const float* bb = beta + (size_t)b * H * N;
    float4 acc[8];
#pragma unroll
    for (int j = 0; j < 8; ++j) acc[j] = make_float4(0.f, 0.f, 0.f, 0.f);
    int nbase = ch * 128 + rep * 32;
    for (int i = 0; i < 32; ++i) {
        int n = nbase + i;
        float4 xv = x4[(size_t)(b * N + n) * 64 + dq];
#pragma unroll
        for (int h = 0; h < 8; ++h) {
            float be = bb[h * N + n];  // uniform -> s_load
            acc[h].x += be * xv.x; acc[h].y += be * xv.y;
            acc[h].z += be * xv.z; acc[h].w += be * xv.w;
        }
    }
#pragma unroll
    for (int j = 0; j < 8; ++j) ps[rep][dq][j] = acc[j];
    __syncthreads();
    int js = t >> 6;
#pragma unroll
    for (int jj = 0; jj < 2; ++jj) {
        int h = js * 2 + jj;
        float4 s = ps[0][dq][h], s1 = ps[1][dq][h], s2 = ps[2][dq][h], s3 = ps[3][dq][h];
        s.x += s1.x + s2.x + s3.x; s.y += s1.y + s2.y + s3.y;
        s.z += s1.z + s2.z + s3.z; s.w += s1.w + s2.w + s3.w;
        float* vp = &vbar[((size_t)b * H + h) * D + dq * 4];
        atomicAdd(vp + 0, s.x); atomicAdd(vp + 1, s.y);
        atomicAdd(vp + 2, s.z); atomicAdd(vp + 3, s.w);
    }
}

// ---- result[b, he] = Wv[he,:].vbar[b,h,:] + bv[he]
__global__ __launch_bounds__(256) void k_result(const float4* __restrict__ Wv4,
                                                const float* __restrict__ bv,
                                                const float4* __restrict__ vbar4,
                                                float* __restrict__ res) {
    __shared__ float Vs[32][260];
    __shared__ float Ws[16][260];
    int t = threadIdx.x, h = blockIdx.x;
    int he0 = h * E + blockIdx.y * 16;
#pragma unroll
    for (int j = 0; j < 8; ++j) {
        int i4 = t + j * 256, r = i4 >> 6, c = i4 & 63;
        *(float4*)&Vs[r][c * 4] = vbar4[(size_t)(r * H + h) * 64 + c];
    }
#pragma unroll
    for (int j = 0; j < 4; ++j) {
        int i4 = t + j * 256, r = i4 >> 6, c = i4 & 63;
        *(float4*)&Ws[r][c * 4] = Wv4[(size_t)(he0 + r) * 64 + c];
    }
    __syncthreads();
    int b = t & 31, rr = t >> 5;
    float a0 = 0.f, a1 = 0.f;
#pragma unroll 4
    for (int c = 0; c < 64; ++c) {
        float4 xv = *(float4*)&Vs[b][c * 4];
        float4 w0 = *(float4*)&Ws[rr][c * 4];
        float4 w1 = *(float4*)&Ws[rr + 8][c * 4];
        a0 += DOT4(w0, xv);
        a1 += DOT4(w1, xv);
    }
    res[(size_t)b * HE + he0 + rr] = a0 + bv[he0 + rr];
    res[(size_t)b * HE + he0 + rr + 8] = a1 + bv[he0 + rr + 8];
}

// ---- out[b,d] = Wo[d,:].result[b,:] + bo[d]   (k-sliced, atomic)
__global__ __launch_bounds__(256) void k_out(const float4* __restrict__ Wo4,
                                             const float* __restrict__ bo,
                                             const float4* __restrict__ res4,
                                             float* __restrict__ out) {
    __shared__ float Rs[32][260];
    __shared__ float Ws[8][260];
    int t = threadIdx.x;
    int d0 = blockIdx.x * 8, k0 = blockIdx.y * 512;
    int b = t & 31, rr = t >> 5;
    float a = 0.f;
    for (int chunk = 0; chunk < 2; ++chunk) {
        int kc4 = (k0 + chunk * 256) >> 2;
#pragma unroll
        for (int j = 0; j < 8; ++j) {
            int i4 = t + j * 256, r = i4 >> 6, c = i4 & 63;
            *(float4*)&Rs[r][c * 4] = res4[(size_t)r * 512 + kc4 + c];
        }
#pragma unroll
        for (int j = 0; j < 2; ++j) {
            int i4 = t + j * 256, r = i4 >> 6, c = i4 & 63;
            *(float4*)&Ws[r][c * 4] = Wo4[(size_t)(d0 + r) * 512 + kc4 + c];
        }
        __syncthreads();
#pragma unroll 4
        for (int c = 0; c < 64; ++c) {
            float4 w = *(float4*)&Ws[rr][c * 4];
            float4 rv = *(float4*)&Rs[b][c * 4];
            a += DOT4(w, rv);
        }
        __syncthreads();
    }
    if (blockIdx.y == 0) a += bo[d0 + rr];
    atomicAdd(&out[b * D + d0 + rr], a);
}

extern "C" void kernel_launch(void* const* d_in, const int* in_sizes, int n_in,
                              void* d_out, int out_size, void* d_ws, size_t ws_size,
                              hipStream_t stream) {
    const float* x    = (const float*)d_in[0];
    const float* Wq   = (const float*)d_in[1];
    // d_in[2] = bq : softmax-invariant, drops out
    const float* Wk   = (const float*)d_in[3];
    const float* bk   = (const float*)d_in[4];
    const float* Wv   = (const float*)d_in[5];
    const float* bv   = (const float*)d_in[6];
    const float* wsum = (const float*)d_in[7];
    // d_in[8] = bs : softmax-invariant, drops out
    const float* Wo   = (const float*)d_in[9];
    const float* bo   = (const float*)d_in[10];
    float* wsf  = (float*)d_ws;
    float* Xbar = wsf + OFF_XBAR;
    float* Vbar = wsf + OFF_VBAR;
    float* Kbar = wsf + OFF_KBAR;
    float* U    = wsf + OFF_U;
    float* LOG  = wsf + OFF_LOG;
    float* RES  = wsf + OFF_RES;

    hipMemsetAsync(wsf, 0, (size_t)(8192 + 65536) * 4, stream);   // Xbar + Vbar
    hipMemsetAsync(d_out, 0, (size_t)B * D * 4, stream);

    k_xbar<<<dim3(B, 8), 256, 0, stream>>>((const float4*)x, wsum, Xbar);
    k_kbar<<<128, 256, 0, stream>>>((const float4*)Wk, bk, wsum, (const float4*)Xbar, Kbar);
    k_u<<<dim3(H, 4), 256, 0, stream>>>((const float4*)Wq, Kbar, U);
    k_logits<<<dim3(B, 16), 256, 0, stream>>>((const float4*)x, U, LOG);
    k_softmax<<<B * H, 256, 0, stream>>>(LOG);
    k_vbar<<<dim3(B, 8), 256, 0, stream>>>((const float4*)x, LOG, Vbar);
    k_result<<<dim3(H, 16), 256, 0, stream>>>((const float4*)Wv, bv, (const float4*)Vbar, RES);
    k_out<<<dim3(32, 4), 256, 0, stream>>>((const float4*)Wo, bo, (const float4*)RES, (float*)d_out);
}